// Round 7
// baseline (139.210 us; speedup 1.0000x reference)
//
#include <hip/hip_runtime.h>

#define NN 128
#define CC_ 16
#define HH 32
#define WW 32
#define DD 4096   // 16*16*16 pooled features per sample
#define ND (NN*DD)

typedef float v2f __attribute__((ext_vector_type(2)));

// c = sqrt(0.5*log2(e)); folded into the means so the per-term exponent is
// exp2(-(q*q)) with the negate absorbed by the v_exp input modifier.
#define MU_SCALE 0.8493218002880191f

// ---------------------------------------------------------------------------
// Kernel 1: fused 2x2 avg-pool, interleaved layout:
//   wm[n*DD+d] = {MU_SCALE*ma, MU_SCALE*mb}, wv[n*DD+d] = {va, vb}
// Thread 0 zeroes d_out (poisoned 0xAA before every launch).
// ---------------------------------------------------------------------------
__global__ __launch_bounds__(256) void pool_kernel(
    const float* __restrict__ mu_a, const float* __restrict__ lv_a,
    const float* __restrict__ mu_b, const float* __restrict__ lv_b,
    float2* __restrict__ wm, float2* __restrict__ wv, float* __restrict__ out)
{
    int t = blockIdx.x * 256 + threadIdx.x;
    if (t == 0) out[0] = 0.0f;

    int wo = t & 15;
    int ho = (t >> 4) & 15;
    int c  = (t >> 8) & 15;
    int n  = t >> 12;

    int base = ((n * CC_ + c) * HH + 2 * ho) * WW + 2 * wo;

    float2 a0 = *(const float2*)(mu_a + base);
    float2 a1 = *(const float2*)(mu_a + base + WW);
    float2 la0 = *(const float2*)(lv_a + base);
    float2 la1 = *(const float2*)(lv_a + base + WW);
    float2 b0 = *(const float2*)(mu_b + base);
    float2 b1 = *(const float2*)(mu_b + base + WW);
    float2 lb0 = *(const float2*)(lv_b + base);
    float2 lb1 = *(const float2*)(lv_b + base + WW);

    const float ms = 0.25f * MU_SCALE;
    float ma_v = ms * (a0.x + a0.y + a1.x + a1.y);
    float mb_v = ms * (b0.x + b0.y + b1.x + b1.y);
    float va_v = 0.0625f * (__expf(la0.x) + __expf(la0.y) + __expf(la1.x) + __expf(la1.y));
    float vb_v = 0.0625f * (__expf(lb0.x) + __expf(lb0.y) + __expf(lb1.x) + __expf(lb1.y));

    wm[t] = make_float2(ma_v, mb_v);
    wv[t] = make_float2(va_v, vb_v);
}

// ---------------------------------------------------------------------------
// Kernel 2: merged, LOAD-BALANCED pair sums. Two uniform block types, each
// exactly 64 packed groups/thread (5 pk + 4 trans per group):
//  TRI (y<136): 8x8 lower-triangle tile (ti>=tj). The {a,b}-interleaved ws
//    layout packs aa in lane.x, bb in lane.y: dd = wm[i]-wm[j]. Diagonal
//    tiles use half-weights {1,.5,0}. Contributes 2*(acc.x+acc.y).
//  AB (y>=136): 4 i-rows x 32 j, a-vs-b term, lanes pack 2 i-rows.
//    Contributes -2*(acc.x+acc.y).
// Grid: x=16 d-chunks, y=264 -> 4224 blocks (~2x resident capacity ->
// dynamic dispatch rebalances; one dispatch = one tail).
// ---------------------------------------------------------------------------
__device__ __forceinline__ void pair_group(
    v2f& acc, v2f mi, v2f mj, v2f vi, v2f vj)
{
    v2f dd = mi - mj;          // v_pk_add
    v2f s  = vi + vj;          // v_pk_add
    v2f r;
    r.x = __builtin_amdgcn_rsqf(s.x);
    r.y = __builtin_amdgcn_rsqf(s.y);
    v2f q  = dd * r;           // v_pk_mul
    v2f qq = q * q;            // v_pk_mul
    v2f e;
    e.x = __builtin_amdgcn_exp2f(-qq.x);
    e.y = __builtin_amdgcn_exp2f(-qq.y);
    acc += e * r;              // v_pk_fma
}

__device__ __forceinline__ void pair_group_w(
    v2f& acc, float w, v2f mi, v2f mj, v2f vi, v2f vj)
{
    v2f dd = mi - mj;
    v2f s  = vi + vj;
    v2f r;
    r.x = __builtin_amdgcn_rsqf(s.x);
    r.y = __builtin_amdgcn_rsqf(s.y);
    v2f q  = dd * r;
    v2f qq = q * q;
    v2f e;
    e.x = __builtin_amdgcn_exp2f(-qq.x);
    e.y = __builtin_amdgcn_exp2f(-qq.y);
    v2f er = e * r;
    acc += (v2f){w, w} * er;
}

__global__ __launch_bounds__(256) void pair_kernel(
    const float2* __restrict__ wm, const float2* __restrict__ wv,
    float* __restrict__ out)
{
    const int d = blockIdx.x * 256 + threadIdx.x;
    const int y = blockIdx.y;

    float part;

    if (y < 136) {
        // ---- TRI: aa+bb over 8x8 lower-triangle tile ----
        int ti = (int)((sqrtf(8.0f * (float)y + 1.0f) - 1.0f) * 0.5f + 1e-4f);
        int tj = y - ti * (ti + 1) / 2;
        const int i0 = ti * 8, j0 = tj * 8;

        v2f pm[8], pv[8];
#pragma unroll
        for (int p = 0; p < 8; ++p) {
            float2 m = wm[(i0 + p) * DD + d];
            float2 v = wv[(i0 + p) * DD + d];
            pm[p] = (v2f){m.x, m.y};
            pv[p] = (v2f){v.x, v.y};
        }

        v2f acc = (v2f){0.0f, 0.0f};
        if (ti != tj) {
#pragma unroll 2
            for (int jj = 0; jj < 8; ++jj) {
                float2 mjf = wm[(j0 + jj) * DD + d];
                float2 vjf = wv[(j0 + jj) * DD + d];
                v2f mj = (v2f){mjf.x, mjf.y};
                v2f vj = (v2f){vjf.x, vjf.y};
#pragma unroll
                for (int p = 0; p < 8; ++p)
                    pair_group(acc, pm[p], mj, pv[p], vj);
            }
        } else {
#pragma unroll 2
            for (int jj = 0; jj < 8; ++jj) {
                float2 mjf = wm[(j0 + jj) * DD + d];
                float2 vjf = wv[(j0 + jj) * DD + d];
                v2f mj = (v2f){mjf.x, mjf.y};
                v2f vj = (v2f){vjf.x, vjf.y};
                int j = j0 + jj;
#pragma unroll
                for (int p = 0; p < 8; ++p) {
                    int i = i0 + p;
                    float w = (j < i) ? 1.0f : ((j == i) ? 0.5f : 0.0f);
                    pair_group_w(acc, w, pm[p], mj, pv[p], vj);
                }
            }
        }
        part = 2.0f * (acc.x + acc.y);
    } else {
        // ---- AB: a-vs-b over 4 i-rows x 32 j ----
        const int y2 = y - 136;
        const int i0 = (y2 >> 2) * 4;
        const int j0 = (y2 & 3) * 32;

        v2f pma[2], pva[2];
#pragma unroll
        for (int p = 0; p < 2; ++p) {
            float2 m0 = wm[(i0 + 2 * p) * DD + d];
            float2 m1 = wm[(i0 + 2 * p + 1) * DD + d];
            float2 v0 = wv[(i0 + 2 * p) * DD + d];
            float2 v1 = wv[(i0 + 2 * p + 1) * DD + d];
            pma[p] = (v2f){m0.x, m1.x};
            pva[p] = (v2f){v0.x, v1.x};
        }

        v2f acc = (v2f){0.0f, 0.0f};
#pragma unroll 2
        for (int j = j0; j < j0 + 32; ++j) {
            float2 jm = wm[j * DD + d];
            float2 jv = wv[j * DD + d];
            v2f jmb2 = (v2f){jm.y, jm.y};
            v2f jvb2 = (v2f){jv.y, jv.y};
#pragma unroll
            for (int p = 0; p < 2; ++p)
                pair_group(acc, pma[p], jmb2, pva[p], jvb2);
        }
        part = -2.0f * (acc.x + acc.y);
    }

    // wave (64-lane) shuffle reduction
#pragma unroll
    for (int off = 32; off > 0; off >>= 1)
        part += __shfl_down(part, off, 64);

    __shared__ float wsum[4];
    int lane = threadIdx.x & 63;
    int wv_  = threadIdx.x >> 6;
    if (lane == 0) wsum[wv_] = part;
    __syncthreads();
    if (threadIdx.x == 0) {
        float s = wsum[0] + wsum[1] + wsum[2] + wsum[3];
        atomicAdd(out, s);
    }
}

extern "C" void kernel_launch(void* const* d_in, const int* in_sizes, int n_in,
                              void* d_out, int out_size, void* d_ws, size_t ws_size,
                              hipStream_t stream) {
    const float* mu_a = (const float*)d_in[0];
    const float* lv_a = (const float*)d_in[1];
    const float* mu_b = (const float*)d_in[2];
    const float* lv_b = (const float*)d_in[3];
    float* out = (float*)d_out;
    float2* wm = (float2*)d_ws;            // ND float2 = 4 MB
    float2* wv = ((float2*)d_ws) + ND;     // ND float2 = 4 MB

    pool_kernel<<<dim3(ND / 256), 256, 0, stream>>>(mu_a, lv_a, mu_b, lv_b, wm, wv, out);
    pair_kernel<<<dim3(DD / 256, 136 + 128), 256, 0, stream>>>(wm, wv, out);
}